// Round 14
// baseline (7428.663 us; speedup 1.0000x reference)
//
#include <hip/hip_runtime.h>

#define B_ 64
#define T_ 512
#define E_ 512
#define H_ 1024
#define C_ 20
#define RING 16
#define BH (B_ * H_)

typedef __attribute__((ext_vector_type(8))) _Float16 f16x8;
typedef __attribute__((ext_vector_type(4))) float f32x4;
typedef unsigned long long u64;

__device__ __forceinline__ void st_agent_u64(u64* p, u64 v){
  __hip_atomic_store(p, v, __ATOMIC_RELAXED, __HIP_MEMORY_SCOPE_AGENT);
}
__device__ __forceinline__ u64 ld_agent_u64(const u64* p){
  return __hip_atomic_load(p, __ATOMIC_RELAXED, __HIP_MEMORY_SCOPE_AGENT);
}

// ---------------------------------------------------------------------------
// Prep: W_hh/W_ih -> fp16, init h-ring (slot0 = h0 = zeros, slots 1..15 =
// 0xFFFF sentinel = fp16 NaN, never produced by tanh). Ring MUST be re-inited
// every launch (ws not re-poisoned between graph replays).
// ---------------------------------------------------------------------------
__global__ void prep_kernel(const float* __restrict__ wih,
                            const float* __restrict__ whh,
                            _Float16* __restrict__ whhF,
                            _Float16* __restrict__ wihF,
                            short* __restrict__ hring)
{
  const long NH = (long)H_ * H_;
  const long NI = (long)H_ * E_;
  const long NR = (long)RING * BH;
  const long TOT = NH + NI + NR;
  long i = (long)blockIdx.x * blockDim.x + threadIdx.x;
  const long stride = (long)gridDim.x * blockDim.x;
  for (; i < TOT; i += stride){
    if (i < NH){
      whhF[i] = (_Float16)whh[i];
    } else if (i < NH + NI){
      long j = i - NH;
      wihF[j] = (_Float16)wih[j];
    } else {
      long j = i - NH - NI;
      hring[j] = (j < BH) ? (short)0 : (short)0xFFFF;
    }
  }
}

// ---------------------------------------------------------------------------
// xp_gemm: xp[t][b][h] = x[b][t][:] @ W_ih[h][:] + b_ih[h] + b_hh[h], fp16,
// stored PRE-SWIZZLED in MFMA C-fragment order: xp[((t*64+cc)*4+bg)*64+lane]
// holds 4 fp16 (col = cc*16 + lane&15, rows bg*16 + (lane>>4)*4 + j).
// (Layout verified in R8/R13-audit: absmax 0.00098.)
// ---------------------------------------------------------------------------
__global__ __launch_bounds__(256, 1) void xp_gemm(
    const float* __restrict__ x, const _Float16* __restrict__ wihF,
    const float* __restrict__ bih, const float* __restrict__ bhh,
    u64* __restrict__ xp)
{
  const int lane = threadIdx.x & 63;
  const int wv   = threadIdx.x >> 6;       // 0..3 -> col quarter
  const int bg   = blockIdx.x & 3;
  const int tb   = (blockIdx.x >> 2) * 4;  // 4 timesteps per block
  const int r16  = lane & 15;
  const int k8   = (lane >> 4) * 8;

  const int brow = bg * 16 + r16;

  f32x4 acc[4][16];
  #pragma unroll
  for (int t = 0; t < 4; t++)
    #pragma unroll
    for (int c = 0; c < 16; c++) acc[t][c] = { 0.f, 0.f, 0.f, 0.f };

  for (int kc = 0; kc < 16; kc++){
    f16x8 a[4];
    #pragma unroll
    for (int t = 0; t < 4; t++){
      const float* xp8 = x + ((long)brow * T_ + tb + t) * E_ + kc * 32 + k8;
      float4 f0 = *(const float4*)xp8;
      float4 f1 = *(const float4*)(xp8 + 4);
      f16x8 v;
      v[0]=(_Float16)f0.x; v[1]=(_Float16)f0.y; v[2]=(_Float16)f0.z; v[3]=(_Float16)f0.w;
      v[4]=(_Float16)f1.x; v[5]=(_Float16)f1.y; v[6]=(_Float16)f1.z; v[7]=(_Float16)f1.w;
      a[t] = v;
    }
    #pragma unroll
    for (int c = 0; c < 16; c++){
      f16x8 b = *(const f16x8*)(wihF + (long)(wv * 256 + c * 16 + r16) * E_ + kc * 32 + k8);
      #pragma unroll
      for (int t = 0; t < 4; t++)
        acc[t][c] = __builtin_amdgcn_mfma_f32_16x16x32_f16(a[t], b, acc[t][c], 0, 0, 0);
    }
  }
  #pragma unroll
  for (int c = 0; c < 16; c++){
    int col = wv * 256 + c * 16 + r16;
    float bs = bih[col] + bhh[col];
    int cc = wv * 16 + c;
    #pragma unroll
    for (int t = 0; t < 4; t++){
      union { _Float16 h[4]; u64 q; } pu;
      #pragma unroll
      for (int j = 0; j < 4; j++) pu.h[j] = (_Float16)(acc[t][c][j] + bs);
      xp[(((long)(tb + t) * 64 + cc) * 4 + bg) * 64 + lane] = pu.q;
    }
  }
}

// ---------------------------------------------------------------------------
// Persistent scan v10: 32 blocks (4 bg x 8 cg) x 256 threads = 4 INDEPENDENT
// waves. Wave w owns [16 batch rows x 32 cols], FULL K=1024:
//  - W_hh slice pinned (256 VGPRs / AGPR-offloaded);
//  - h(t) polled via COMPILER-MANAGED relaxed agent u64 loads (pairs per 16B
//    chunk). R13 lesson: inline-asm load destinations must NOT live across
//    the loop back-edge (register allocator may reuse an in-flight dest ->
//    silent corruption). __hip_atomic_load lets the compiler track liveness
//    and insert the s_waitcnt itself — pre-issue across iterations is legal.
//  - no LDS for h, no barriers, no K-reduce; fan-in 8; arrival-order fused
//    MFMAs (chunk's 2 MFMAs fire when its two granules validate).
//  - tail order: publish h(t+1) -> re-sentinel slot t+8 -> pre-issue next
//    step's 64 poll loads (overlaps publish->visibility window).
// Protocol (R4-R12): 16-slot sentinel ring, 8B single-copy-atomic granules,
// 0xFFFF fp16-NaN sentinel, re-sentinel slot t+8 (7-step window; commit
// ordered by the compiler's per-use waits across 7 iterations).
// ---------------------------------------------------------------------------
__global__ __launch_bounds__(256, 1) void rnn_scan(
    const u64* __restrict__ xp, const _Float16* __restrict__ whhF,
    _Float16* __restrict__ hring, float* __restrict__ hT)
{
  const int tid  = threadIdx.x;
  const int lane = tid & 63;
  const int w    = tid >> 6;          // wave 0..3 (independent)
  const int bg   = blockIdx.x & 3;    // batch group (16 rows)
  const int cg   = blockIdx.x >> 2;   // col group 0..7 (128 cols/block)
  const int r16  = lane & 15;
  const int k8   = (lane >> 4) * 8;

  __shared__ float tile[4][16][36];   // per-wave 16x32 f32 transpose buffer

  // --- pinned W_hh: 2 col-subtiles x 32 K-chunks = 256 regs ---
  f16x8 wh[2][32];
  #pragma unroll
  for (int ct = 0; ct < 2; ct++)
    #pragma unroll
    for (int kc = 0; kc < 32; kc++)
      wh[ct][kc] = *(const f16x8*)(whhF +
          (long)(cg * 128 + w * 32 + ct * 16 + r16) * H_ + kc * 32 + k8);
  #pragma unroll
  for (int ct = 0; ct < 2; ct++)
    #pragma unroll
    for (int kc = 0; kc < 32; kc++)
      asm volatile("" : "+v"(wh[ct][kc]));

  // consumer A-frag base: row = bg*16 + r16, k = kc*32 + k8
  const long haOff = (long)(bg * 16 + r16) * H_ + k8;
  // publisher: row = lane>>2, cols (lane&3)*8 .. +8 of the wave's 32 cols
  const long pubOff = (long)(bg * 16 + (lane >> 2)) * H_
                      + cg * 128 + w * 32 + (lane & 3) * 8;
  const int cc0 = cg * 8 + w * 2;     // xp col-chunk ids: cc0, cc0+1

  // xp(0)
  u64 xq0 = xp[((long)cc0 * 4 + bg) * 64 + lane];
  u64 xq1 = xp[((long)(cc0 + 1) * 4 + bg) * 64 + lane];

  // prologue: pre-issue poll loads for t=0 (slot 0 = h0 zeros, valid)
  u64 p0[32], p1[32];
  #pragma unroll
  for (int c = 0; c < 32; c++){
    const u64* g = (const u64*)(hring + haOff + c * 32);
    p0[c] = ld_agent_u64(g);
    p1[c] = ld_agent_u64(g + 1);
  }

  for (int t = 0; t < T_; ++t){
    const _Float16* hb = hring + (long)(t & (RING - 1)) * BH + haOff;

    // ---- acc init from xp(t) (prefetched last iteration) ----
    f32x4 acc0, acc1;
    {
      const _Float16* q0 = (const _Float16*)&xq0;
      const _Float16* q1 = (const _Float16*)&xq1;
      #pragma unroll
      for (int j = 0; j < 4; j++){ acc0[j] = (float)q0[j]; acc1[j] = (float)q1[j]; }
    }

    // ---- validate + arrival-order fused MFMAs over 32 chunks ----
    unsigned need = 0xFFFFFFFFu;
    while (true){
      #pragma unroll
      for (int c = 0; c < 32; c++){
        if (need & (1u << c)){
          bool bad = (((unsigned)p0[c] & 0xFFFFu) == 0xFFFFu) ||
                     (((unsigned)p1[c] & 0xFFFFu) == 0xFFFFu);
          if (!__any(bad)){
            union { u64 q[2]; f16x8 v; } hu;
            hu.q[0] = p0[c]; hu.q[1] = p1[c];
            acc0 = __builtin_amdgcn_mfma_f32_16x16x32_f16(hu.v, wh[0][c], acc0, 0, 0, 0);
            acc1 = __builtin_amdgcn_mfma_f32_16x16x32_f16(hu.v, wh[1][c], acc1, 0, 0, 0);
            need &= ~(1u << c);
          }
        }
      }
      if (!need) break;
      #pragma unroll
      for (int c = 0; c < 32; c++){
        if (need & (1u << c)){
          const u64* g = (const u64*)(hb + c * 32);
          p0[c] = ld_agent_u64(g);
          p1[c] = ld_agent_u64(g + 1);
        }
      }
    }

    // ---- xp prefetch for t+1 (cached; ~full step of flight) ----
    if (t + 1 < T_){
      xq0 = xp[(((long)(t + 1) * 64 + cc0) * 4 + bg) * 64 + lane];
      xq1 = xp[(((long)(t + 1) * 64 + cc0 + 1) * 4 + bg) * 64 + lane];
    }

    // ---- tanh ----
    float hv[2][4];
    #pragma unroll
    for (int j = 0; j < 4; j++){
      float s = acc0[j], a = fabsf(s), ex = __expf(-2.f * a);
      hv[0][j] = copysignf((1.f - ex) / (1.f + ex), s);
      s = acc1[j]; a = fabsf(s); ex = __expf(-2.f * a);
      hv[1][j] = copysignf((1.f - ex) / (1.f + ex), s);
    }

    // ---- in-wave LDS transpose: C-frag (col=r16, row=(lane>>4)*4+j) ->
    //      row-granules (row=lane>>2, 8 cols) ----
    #pragma unroll
    for (int j = 0; j < 4; j++){
      tile[w][(lane >> 4) * 4 + j][r16]      = hv[0][j];
      tile[w][(lane >> 4) * 4 + j][16 + r16] = hv[1][j];
    }
    f32x4 o0 = *(const f32x4*)&tile[w][lane >> 2][(lane & 3) * 8];
    f32x4 o1 = *(const f32x4*)&tile[w][lane >> 2][(lane & 3) * 8 + 4];

    if (t < T_ - 1){
      // ---- publish 2 granules, re-sentinel slot t+8, pre-issue next polls ----
      union { _Float16 h[4]; u64 q; } g0, g1;
      #pragma unroll
      for (int j = 0; j < 4; j++){ g0.h[j] = (_Float16)o0[j]; g1.h[j] = (_Float16)o1[j]; }
      _Float16* hn = hring + (long)((t + 1) & (RING - 1)) * BH;
      st_agent_u64((u64*)(hn + pubOff), g0.q);
      st_agent_u64((u64*)(hn + pubOff + 4), g1.q);
      if (t + 8 < T_){
        _Float16* hs = hring + (long)((t + 8) & (RING - 1)) * BH;
        st_agent_u64((u64*)(hs + pubOff), 0xFFFFFFFFFFFFFFFFull);
        st_agent_u64((u64*)(hs + pubOff + 4), 0xFFFFFFFFFFFFFFFFull);
      }
      const _Float16* hb1 = hring + (long)((t + 1) & (RING - 1)) * BH + haOff;
      #pragma unroll
      for (int c = 0; c < 32; c++){
        const u64* g = (const u64*)(hb1 + c * 32);
        p0[c] = ld_agent_u64(g);
        p1[c] = ld_agent_u64(g + 1);
      }
    } else {
      *(float4*)(hT + pubOff)     = make_float4(o0[0], o0[1], o0[2], o0[3]);
      *(float4*)(hT + pubOff + 4) = make_float4(o1[0], o1[1], o1[2], o1[3]);
    }
  }
}

// ---------------------------------------------------------------------------
// Head: y1 = relu(hT @ fc1_w^T + b1);  out = y1 @ fc2_w^T + b2   (all fp32)
// ---------------------------------------------------------------------------
__global__ void fc1_kernel(const float* __restrict__ hT, const float* __restrict__ w1,
                           const float* __restrict__ b1, float* __restrict__ y1)
{
  int o = blockIdx.x * 256 + threadIdx.x;     // 0..65535
  int b = o >> 10, j = o & 1023;
  const float4* hp = (const float4*)(hT + (long)b * H_);
  const float4* wp = (const float4*)(w1 + (long)j * H_);
  float s = 0.f;
  #pragma unroll 4
  for (int k = 0; k < H_ / 4; k++){
    float4 hv = hp[k], wv = wp[k];
    s += hv.x * wv.x + hv.y * wv.y + hv.z * wv.z + hv.w * wv.w;
  }
  s += b1[j];
  y1[o] = s > 0.f ? s : 0.f;
}

__global__ void fc2_kernel(const float* __restrict__ y1, const float* __restrict__ w2,
                           const float* __restrict__ b2, float* __restrict__ out)
{
  __shared__ float ybuf[H_];
  int b = blockIdx.x;
  for (int k = threadIdx.x; k < H_; k += 256) ybuf[k] = y1[(long)b * H_ + k];
  __syncthreads();
  if (threadIdx.x < C_){
    const float* wp = w2 + (long)threadIdx.x * H_;
    float s = 0.f;
    for (int k = 0; k < H_; k++) s += ybuf[k] * wp[k];
    out[b * C_ + threadIdx.x] = s + b2[threadIdx.x];
  }
}

// ---------------------------------------------------------------------------
extern "C" void kernel_launch(void* const* d_in, const int* in_sizes, int n_in,
                              void* d_out, int out_size, void* d_ws, size_t ws_size,
                              hipStream_t stream)
{
  const float* x   = (const float*)d_in[0];
  const float* wih = (const float*)d_in[1];
  const float* whh = (const float*)d_in[2];
  const float* bih = (const float*)d_in[3];
  const float* bhh = (const float*)d_in[4];
  const float* w1  = (const float*)d_in[5];
  const float* b1  = (const float*)d_in[6];
  const float* w2  = (const float*)d_in[7];
  const float* b2  = (const float*)d_in[8];
  float* out = (float*)d_out;

  char* ws = (char*)d_ws;
  size_t off = 0;
  auto carve = [&](size_t bytes) -> char* {
    char* p = ws + off; off += (bytes + 255) & ~(size_t)255; return p;
  };
  _Float16* whhF  = (_Float16*)carve((size_t)H_ * H_ * 2);
  _Float16* wihF  = (_Float16*)carve((size_t)H_ * E_ * 2);
  _Float16* hring = (_Float16*)carve((size_t)RING * BH * 2);
  float*    hT    = (float*)carve((size_t)B_ * H_ * 4);
  float*    y1    = (float*)carve((size_t)B_ * H_ * 4);
  u64*      xp    = (u64*)carve((size_t)T_ * 64 * 4 * 64 * 8);   // 64 MB

  prep_kernel<<<1024, 256, 0, stream>>>(wih, whh, whhF, wihF, (short*)hring);
  xp_gemm<<<512, 256, 0, stream>>>(x, wihF, bih, bhh, xp);
  rnn_scan<<<32, 256, 0, stream>>>(xp, whhF, hring, hT);
  fc1_kernel<<<256, 256, 0, stream>>>(hT, w1, b1, y1);
  fc2_kernel<<<64, 256, 0, stream>>>(y1, w2, b2, out);
}

// Round 15
// 3523.635 us; speedup vs baseline: 2.1082x; 2.1082x over previous
//
#include <hip/hip_runtime.h>

#define B_ 64
#define T_ 512
#define E_ 512
#define H_ 1024
#define C_ 20
#define RING 16
#define BH (B_ * H_)

typedef __attribute__((ext_vector_type(8))) _Float16 f16x8;
typedef __attribute__((ext_vector_type(4))) float f32x4;
typedef __attribute__((ext_vector_type(4))) unsigned int u32x4;
typedef unsigned long long u64;

__device__ __forceinline__ void st_agent_u64(u64* p, u64 v){
  __hip_atomic_store(p, v, __ATOMIC_RELAXED, __HIP_MEMORY_SCOPE_AGENT);
}
// Coherent 16B load (bypasses L1/L2, reads the device-coherent point).
// Issued AND consumed within one loop iteration only (R13/R14 lesson:
// asm dests must not live across the back edge; compiler atomics serialize).
__device__ __forceinline__ u32x4 ld_b128_cohere(const void* p){
  u32x4 r;
  asm volatile("global_load_dwordx4 %0, %1, off sc0 sc1"
               : "=v"(r) : "v"(p) : "memory");
  return r;
}

// ---------------------------------------------------------------------------
// Prep: W_hh/W_ih -> fp16, init h-ring (slot0 = h0 = zeros, slots 1..15 =
// 0xFFFF sentinel = fp16 NaN, never produced by tanh). Ring MUST be re-inited
// every launch (ws not re-poisoned between graph replays).
// ---------------------------------------------------------------------------
__global__ void prep_kernel(const float* __restrict__ wih,
                            const float* __restrict__ whh,
                            _Float16* __restrict__ whhF,
                            _Float16* __restrict__ wihF,
                            short* __restrict__ hring)
{
  const long NH = (long)H_ * H_;
  const long NI = (long)H_ * E_;
  const long NR = (long)RING * BH;
  const long TOT = NH + NI + NR;
  long i = (long)blockIdx.x * blockDim.x + threadIdx.x;
  const long stride = (long)gridDim.x * blockDim.x;
  for (; i < TOT; i += stride){
    if (i < NH){
      whhF[i] = (_Float16)whh[i];
    } else if (i < NH + NI){
      long j = i - NH;
      wihF[j] = (_Float16)wih[j];
    } else {
      long j = i - NH - NI;
      hring[j] = (j < BH) ? (short)0 : (short)0xFFFF;
    }
  }
}

// ---------------------------------------------------------------------------
// Persistent scan v11 = v8 (R12, proven 1403us) + two upgrades:
//  (1) parity double-buffered LDS partials -> ONE lgkm-only barrier per step.
//      Safety: wave A reaches write(t+2) (same buffer as t) only after
//      barrier-1(t+1), which requires every wave past reduce(t).
//  (2) input projection FUSED into the scan (xp_gemm deleted): each wave
//      pins W_ih[128 cols x 64 E] (16 f16x8) beside its W_hh slice and
//      computes xpacc(t+1) = x(t+1) @ W_ih^T during step t's idle MFMA
//      window (after partials-write, before barrier). x is staged TWO steps
//      ahead via plain compiler-managed loads (legal across back edges).
//      Step t's recurrent acc initializes from xpacc(t); bias (bih+bhh)
//      added once at the reducer from registers. xp stays fp32 end-to-end.
//
// Geometry (v8): 32 blocks (4 bg x 8 cg) x 512 threads (8 waves). Block owns
// [16 rows x 128 cols]; K=1024 split over 8 waves (128 K each); wave w's
// K-slice lies entirely in producer block (bg, w): FAN-IN 1 PER WAVE,
// poll payload 4 KB/wave.
// Exchange protocol (proven R4-R12): 16-slot sentinel ring, 8B single-copy-
// atomic granules, 0xFFFF fp16-NaN sentinel, re-sentinel slot t+8,
// arrival-order fused MFMAs, relaxed agent stores, bulk asm coherent loads.
// ---------------------------------------------------------------------------
__global__ __launch_bounds__(512, 1) void rnn_scan(
    const float* __restrict__ x, const _Float16* __restrict__ wihF,
    const _Float16* __restrict__ whhF,
    const float* __restrict__ bih, const float* __restrict__ bhh,
    _Float16* __restrict__ hring, float* __restrict__ hT)
{
  const int tid  = threadIdx.x;
  const int lane = tid & 63;
  const int w    = tid >> 6;          // wave 0..7: K-slice == producer cg'
  const int bg   = blockIdx.x & 3;    // batch group (16 rows)
  const int cg   = blockIdx.x >> 2;   // col group 0..7 (128 cols)
  const int r16  = lane & 15;
  const int kq   = lane >> 4;         // 0..3
  const int k8   = kq * 8;

  __shared__ float part[2][8][16][132];   // parity dbuf, 132 KB

  // --- pinned W_hh fragments: [col-tile ct 0..7][K-chunk kc 0..3] ---
  f16x8 wh[8][4];
  #pragma unroll
  for (int ct = 0; ct < 8; ct++)
    #pragma unroll
    for (int kc = 0; kc < 4; kc++)
      wh[ct][kc] = *(const f16x8*)(whhF +
          (long)(cg * 128 + ct * 16 + r16) * H_ + w * 128 + kc * 32 + k8);
  // --- pinned W_ih fragments: [col-tile ct 0..7][E-chunk ec 0..1] ---
  f16x8 wi[8][2];
  #pragma unroll
  for (int ct = 0; ct < 8; ct++)
    #pragma unroll
    for (int ec = 0; ec < 2; ec++)
      wi[ct][ec] = *(const f16x8*)(wihF +
          (long)(cg * 128 + ct * 16 + r16) * E_ + w * 64 + ec * 32 + k8);
  #pragma unroll
  for (int ct = 0; ct < 8; ct++){
    #pragma unroll
    for (int kc = 0; kc < 4; kc++) asm volatile("" : "+v"(wh[ct][kc]));
    asm volatile("" : "+v"(wi[ct][0]), "+v"(wi[ct][1]));
  }

  // consumer A-frag base: row = bg*16 + r16, k = w*128 + kc*32 + k8
  const long haOff = (long)(bg * 16 + r16) * H_ + w * 128 + k8;
  // reducer/publisher mapping: thread -> (row rr, col-quad cc4)
  const int  rr  = tid >> 5;          // 0..15
  const int  cc4 = tid & 31;          // 0..31 (4 cols each)
  const long pubOff = (long)(bg * 16 + rr) * H_ + cg * 128 + cc4 * 4;

  // reducer bias (bih+bhh) for this thread's 4 cols
  f32x4 bias4;
  #pragma unroll
  for (int j = 0; j < 4; j++){
    int col = cg * 128 + cc4 * 4 + j;
    bias4[j] = bih[col] + bhh[col];
  }

  // x A-frag loader: rows bg*16+r16, E-offset w*64 + ec*32 + k8 (8 fp32)
  auto load_xa = [&](int tn, int ec) -> f16x8 {
    const float* xp8 = x + ((long)(bg * 16 + r16) * T_ + tn) * E_
                         + w * 64 + ec * 32 + k8;
    float4 f0 = *(const float4*)xp8;
    float4 f1 = *(const float4*)(xp8 + 4);
    f16x8 v;
    v[0]=(_Float16)f0.x; v[1]=(_Float16)f0.y; v[2]=(_Float16)f0.z; v[3]=(_Float16)f0.w;
    v[4]=(_Float16)f1.x; v[5]=(_Float16)f1.y; v[6]=(_Float16)f1.z; v[7]=(_Float16)f1.w;
    return v;
  };

  // prologue: xpacc(0) directly from x(0); stage x(1) into xa_cur
  f32x4 xpacc[8];
  {
    f16x8 xa0 = load_xa(0, 0), xa1 = load_xa(0, 1);
    #pragma unroll
    for (int ct = 0; ct < 8; ct++){
      f32x4 z = { 0.f, 0.f, 0.f, 0.f };
      z = __builtin_amdgcn_mfma_f32_16x16x32_f16(xa0, wi[ct][0], z, 0, 0, 0);
      z = __builtin_amdgcn_mfma_f32_16x16x32_f16(xa1, wi[ct][1], z, 0, 0, 0);
      xpacc[ct] = z;
    }
  }
  f16x8 xa_cur[2], xa_nxt[2];
  xa_cur[0] = load_xa(1, 0); xa_cur[1] = load_xa(1, 1);

  for (int t = 0; t < T_; ++t){
    // ---- poll h(t): 4 x 16B coherent loads from ONE producer ----
    const _Float16* hb = hring + (long)(t & (RING - 1)) * BH + haOff;
    u32x4 q[4];
    #pragma unroll
    for (int c = 0; c < 4; c++) q[c] = ld_b128_cohere(hb + c * 32);
    asm volatile("s_waitcnt vmcnt(0)" ::: "memory");
    __builtin_amdgcn_sched_barrier(0);

    // acc init = this step's input-projection partial (computed last iter)
    f32x4 acc[8];
    #pragma unroll
    for (int ct = 0; ct < 8; ct++) acc[ct] = xpacc[ct];

    // ---- validate + arrival-order fused recurrent MFMAs ----
    unsigned need = 0xFu;
    while (true){
      #pragma unroll
      for (int c = 0; c < 4; c++){
        if (need & (1u << c)){
          bool bad = ((q[c][0] & 0xFFFFu) == 0xFFFFu) ||
                     ((q[c][2] & 0xFFFFu) == 0xFFFFu);
          if (!__any(bad)){
            union { u32x4 u; f16x8 v; } hu; hu.u = q[c];
            #pragma unroll
            for (int ct = 0; ct < 8; ct++)
              acc[ct] = __builtin_amdgcn_mfma_f32_16x16x32_f16(hu.v, wh[ct][c], acc[ct], 0, 0, 0);
            need &= ~(1u << c);
          }
        }
      }
      if (!need) break;
      #pragma unroll
      for (int c = 0; c < 4; c++)
        if (need & (1u << c)) q[c] = ld_b128_cohere(hb + c * 32);
      asm volatile("s_waitcnt vmcnt(0)" ::: "memory");
      __builtin_amdgcn_sched_barrier(0);
    }

    // ---- partials to LDS (parity buffer) ----
    {
      float (*buf)[16][132] = part[t & 1];
      #pragma unroll
      for (int ct = 0; ct < 8; ct++)
        #pragma unroll
        for (int j = 0; j < 4; j++)
          buf[w][kq * 4 + j][ct * 16 + r16] = acc[ct][j];
    }

    // ---- fused input projection for t+1 (idle MFMA window, pre-barrier) ----
    if (t + 1 < T_){
      #pragma unroll
      for (int ct = 0; ct < 8; ct++){
        f32x4 z = { 0.f, 0.f, 0.f, 0.f };
        z = __builtin_amdgcn_mfma_f32_16x16x32_f16(xa_cur[0], wi[ct][0], z, 0, 0, 0);
        z = __builtin_amdgcn_mfma_f32_16x16x32_f16(xa_cur[1], wi[ct][1], z, 0, 0, 0);
        xpacc[ct] = z;
      }
      if (t + 2 < T_){
        xa_nxt[0] = load_xa(t + 2, 0);
        xa_nxt[1] = load_xa(t + 2, 1);
      }
    }

    // ---- single lgkm-only barrier (dbuf removes the WAR barrier) ----
    asm volatile("s_waitcnt lgkmcnt(0)\n\ts_barrier" ::: "memory");

    // ---- reduce 8 waves' partials + bias, tanh, publish ----
    {
      const float (*buf)[16][132] = part[t & 1];
      f32x4 s = bias4;
      #pragma unroll
      for (int p = 0; p < 8; p++)
        s += *(const f32x4*)&buf[p][rr][cc4 * 4];
      float hv[4];
      #pragma unroll
      for (int j = 0; j < 4; j++){
        float v = s[j];
        float a = fabsf(v), ex = __expf(-2.f * a);
        hv[j] = copysignf((1.f - ex) / (1.f + ex), v);
      }

      if (t < T_ - 1){
        union { _Float16 h[4]; u64 q; } g;
        #pragma unroll
        for (int j = 0; j < 4; j++) g.h[j] = (_Float16)hv[j];
        st_agent_u64((u64*)(hring + (long)((t + 1) & (RING - 1)) * BH + pubOff), g.q);
        if (t + 8 < T_)
          st_agent_u64((u64*)(hring + (long)((t + 8) & (RING - 1)) * BH + pubOff),
                       0xFFFFFFFFFFFFFFFFull);
      } else {
        *(float4*)(hT + pubOff) = make_float4(hv[0], hv[1], hv[2], hv[3]);
      }
    }

    // rotate x staging (xa_nxt consumed next iteration)
    xa_cur[0] = xa_nxt[0]; xa_cur[1] = xa_nxt[1];
  }
}

// ---------------------------------------------------------------------------
// Head: y1 = relu(hT @ fc1_w^T + b1);  out = y1 @ fc2_w^T + b2   (all fp32)
// ---------------------------------------------------------------------------
__global__ void fc1_kernel(const float* __restrict__ hT, const float* __restrict__ w1,
                           const float* __restrict__ b1, float* __restrict__ y1)
{
  int o = blockIdx.x * 256 + threadIdx.x;     // 0..65535
  int b = o >> 10, j = o & 1023;
  const float4* hp = (const float4*)(hT + (long)b * H_);
  const float4* wp = (const float4*)(w1 + (long)j * H_);
  float s = 0.f;
  #pragma unroll 4
  for (int k = 0; k < H_ / 4; k++){
    float4 hv = hp[k], wv = wp[k];
    s += hv.x * wv.x + hv.y * wv.y + hv.z * wv.z + hv.w * wv.w;
  }
  s += b1[j];
  y1[o] = s > 0.f ? s : 0.f;
}

__global__ void fc2_kernel(const float* __restrict__ y1, const float* __restrict__ w2,
                           const float* __restrict__ b2, float* __restrict__ out)
{
  __shared__ float ybuf[H_];
  int b = blockIdx.x;
  for (int k = threadIdx.x; k < H_; k += 256) ybuf[k] = y1[(long)b * H_ + k];
  __syncthreads();
  if (threadIdx.x < C_){
    const float* wp = w2 + (long)threadIdx.x * H_;
    float s = 0.f;
    for (int k = 0; k < H_; k++) s += ybuf[k] * wp[k];
    out[b * C_ + threadIdx.x] = s + b2[threadIdx.x];
  }
}

// ---------------------------------------------------------------------------
extern "C" void kernel_launch(void* const* d_in, const int* in_sizes, int n_in,
                              void* d_out, int out_size, void* d_ws, size_t ws_size,
                              hipStream_t stream)
{
  const float* x   = (const float*)d_in[0];
  const float* wih = (const float*)d_in[1];
  const float* whh = (const float*)d_in[2];
  const float* bih = (const float*)d_in[3];
  const float* bhh = (const float*)d_in[4];
  const float* w1  = (const float*)d_in[5];
  const float* b1  = (const float*)d_in[6];
  const float* w2  = (const float*)d_in[7];
  const float* b2  = (const float*)d_in[8];
  float* out = (float*)d_out;

  char* ws = (char*)d_ws;
  size_t off = 0;
  auto carve = [&](size_t bytes) -> char* {
    char* p = ws + off; off += (bytes + 255) & ~(size_t)255; return p;
  };
  _Float16* whhF  = (_Float16*)carve((size_t)H_ * H_ * 2);
  _Float16* wihF  = (_Float16*)carve((size_t)H_ * E_ * 2);
  _Float16* hring = (_Float16*)carve((size_t)RING * BH * 2);
  float*    hT    = (float*)carve((size_t)B_ * H_ * 4);
  float*    y1    = (float*)carve((size_t)B_ * H_ * 4);

  prep_kernel<<<1024, 256, 0, stream>>>(wih, whh, whhF, wihF, (short*)hring);
  rnn_scan<<<32, 512, 0, stream>>>(x, wihF, whhF, bih, bhh, hring, hT);
  fc1_kernel<<<256, 256, 0, stream>>>(hT, w1, b1, y1);
  fc2_kernel<<<64, 256, 0, stream>>>(y1, w2, b2, out);
}

// Round 16
// 1745.038 us; speedup vs baseline: 4.2570x; 2.0192x over previous
//
#include <hip/hip_runtime.h>

#define B_ 64
#define T_ 512
#define E_ 512
#define H_ 1024
#define C_ 20
#define RING 16
#define BH (B_ * H_)

typedef __attribute__((ext_vector_type(8))) _Float16 f16x8;
typedef __attribute__((ext_vector_type(4))) float f32x4;
typedef __attribute__((ext_vector_type(4))) unsigned int u32x4;
typedef unsigned long long u64;

__device__ __forceinline__ void st_agent_u64(u64* p, u64 v){
  __hip_atomic_store(p, v, __ATOMIC_RELAXED, __HIP_MEMORY_SCOPE_AGENT);
}
// Coherent 16B load (bypasses L1/L2, reads the device-coherent point).
// Issued AND consumed within one loop iteration only (R13/R14 lesson:
// asm dests must not live across the back edge; compiler atomics serialize).
__device__ __forceinline__ u32x4 ld_b128_cohere(const void* p){
  u32x4 r;
  asm volatile("global_load_dwordx4 %0, %1, off sc0 sc1"
               : "=v"(r) : "v"(p) : "memory");
  return r;
}

// ---------------------------------------------------------------------------
// Prep: W_hh/W_ih -> fp16, init h-ring (slot0 = h0 = zeros, slots 1..15 =
// 0xFFFF sentinel = fp16 NaN, never produced by tanh). Ring MUST be re-inited
// every launch (ws not re-poisoned between graph replays).
// ---------------------------------------------------------------------------
__global__ void prep_kernel(const float* __restrict__ wih,
                            const float* __restrict__ whh,
                            _Float16* __restrict__ whhF,
                            _Float16* __restrict__ wihF,
                            short* __restrict__ hring)
{
  const long NH = (long)H_ * H_;
  const long NI = (long)H_ * E_;
  const long NR = (long)RING * BH;
  const long TOT = NH + NI + NR;
  long i = (long)blockIdx.x * blockDim.x + threadIdx.x;
  const long stride = (long)gridDim.x * blockDim.x;
  for (; i < TOT; i += stride){
    if (i < NH){
      whhF[i] = (_Float16)whh[i];
    } else if (i < NH + NI){
      long j = i - NH;
      wihF[j] = (_Float16)wih[j];
    } else {
      long j = i - NH - NI;
      hring[j] = (j < BH) ? (short)0 : (short)0xFFFF;
    }
  }
}

// ---------------------------------------------------------------------------
// xp_gemm: xp[t][b][h] = x[b][t][:] @ W_ih[h][:] + b_ih[h] + b_hh[h], fp16,
// stored PLAIN [t][b][h] (the scan adds xp at the reducer stage: 4 contiguous
// fp16 = one 8B read per thread).
// ---------------------------------------------------------------------------
__global__ __launch_bounds__(256, 1) void xp_gemm(
    const float* __restrict__ x, const _Float16* __restrict__ wihF,
    const float* __restrict__ bih, const float* __restrict__ bhh,
    _Float16* __restrict__ xp)
{
  const int lane = threadIdx.x & 63;
  const int wv   = threadIdx.x >> 6;       // 0..3 -> col quarter
  const int bg   = blockIdx.x & 3;
  const int tb   = (blockIdx.x >> 2) * 4;  // 4 timesteps per block
  const int r16  = lane & 15;
  const int k8   = (lane >> 4) * 8;

  const int brow = bg * 16 + r16;

  f32x4 acc[4][16];
  #pragma unroll
  for (int t = 0; t < 4; t++)
    #pragma unroll
    for (int c = 0; c < 16; c++) acc[t][c] = { 0.f, 0.f, 0.f, 0.f };

  for (int kc = 0; kc < 16; kc++){
    f16x8 a[4];
    #pragma unroll
    for (int t = 0; t < 4; t++){
      const float* xp8 = x + ((long)brow * T_ + tb + t) * E_ + kc * 32 + k8;
      float4 f0 = *(const float4*)xp8;
      float4 f1 = *(const float4*)(xp8 + 4);
      f16x8 v;
      v[0]=(_Float16)f0.x; v[1]=(_Float16)f0.y; v[2]=(_Float16)f0.z; v[3]=(_Float16)f0.w;
      v[4]=(_Float16)f1.x; v[5]=(_Float16)f1.y; v[6]=(_Float16)f1.z; v[7]=(_Float16)f1.w;
      a[t] = v;
    }
    #pragma unroll
    for (int c = 0; c < 16; c++){
      f16x8 b = *(const f16x8*)(wihF + (long)(wv * 256 + c * 16 + r16) * E_ + kc * 32 + k8);
      #pragma unroll
      for (int t = 0; t < 4; t++)
        acc[t][c] = __builtin_amdgcn_mfma_f32_16x16x32_f16(a[t], b, acc[t][c], 0, 0, 0);
    }
  }
  // C-frag: col = wv*256 + c*16 + (lane&15); row = bg*16 + (lane>>4)*4 + j
  #pragma unroll
  for (int c = 0; c < 16; c++){
    int col = wv * 256 + c * 16 + r16;
    float bs = bih[col] + bhh[col];
    #pragma unroll
    for (int t = 0; t < 4; t++){
      #pragma unroll
      for (int j = 0; j < 4; j++){
        int row = bg * 16 + (lane >> 4) * 4 + j;
        xp[((long)(tb + t)) * BH + (long)row * H_ + col] =
            (_Float16)(acc[t][c][j] + bs);
      }
    }
  }
}

// ---------------------------------------------------------------------------
// Persistent scan v12 = v8 (R12, proven 1403us) + ONE change: parity
// double-buffered LDS partials -> barrier-2 deleted.
// Safety: wave A reaches write(t+2) (same parity buffer as t) only after the
// barrier of step t+1, which requires every wave past reduce(t) — WAR on the
// parity buffer is impossible with the single per-step barrier.
//
// Geometry (v8): 32 blocks (4 bg x 8 cg) x 512 threads (8 waves). Block owns
// [16 rows x 128 cols]; K=1024 split over 8 waves (128 K each); wave w's
// K-slice lies entirely in producer block (bg, w): FAN-IN 1 PER WAVE,
// poll payload 4 KB/wave (4 x 16B per lane). Weights 32 KB/wave pinned.
//
// Per-step pipeline discipline (v8):
//  - poll loads are the only vmem in flight during the poll;
//  - xp(t+1) prefetch (one 8B cached load) issued immediately after the poll
//    exits -> HBM latency hidden under LDS write + reduce + next poll flight;
//  - publish BEFORE the (now only) next-step barrier for earliest visibility.
// Exchange protocol (proven R4-R12): 16-slot sentinel ring, 8B single-copy-
// atomic granules, 0xFFFF fp16-NaN sentinel, re-sentinel slot t+8,
// arrival-order fused MFMAs, relaxed agent stores, bulk asm coherent loads.
// ---------------------------------------------------------------------------
__global__ __launch_bounds__(512, 1) void rnn_scan(
    const _Float16* __restrict__ xp, const _Float16* __restrict__ whhF,
    _Float16* __restrict__ hring, float* __restrict__ hT)
{
  const int tid  = threadIdx.x;
  const int lane = tid & 63;
  const int w    = tid >> 6;          // wave 0..7: K-slice == producer cg'
  const int bg   = blockIdx.x & 3;    // batch group (16 rows)
  const int cg   = blockIdx.x >> 2;   // col group 0..7 (128 cols)
  const int r16  = lane & 15;
  const int kq   = lane >> 4;         // 0..3

  __shared__ float part[2][8][16][132];   // parity dbuf [buf][wave][row][col+pad]

  // --- pinned W_hh fragments: [col-tile ct 0..7][K-chunk kc 0..3] ---
  f16x8 wh[8][4];
  #pragma unroll
  for (int ct = 0; ct < 8; ct++)
    #pragma unroll
    for (int kc = 0; kc < 4; kc++)
      wh[ct][kc] = *(const f16x8*)(whhF +
          (long)(cg * 128 + ct * 16 + r16) * H_ + w * 128 + kc * 32 + kq * 8);
  #pragma unroll
  for (int ct = 0; ct < 8; ct++)
    #pragma unroll
    for (int kc = 0; kc < 4; kc++)
      asm volatile("" : "+v"(wh[ct][kc]));

  // consumer A-frag base: row = bg*16 + r16, K = w*128 + kc*32 + kq*8
  const long haOff = (long)(bg * 16 + r16) * H_ + w * 128 + kq * 8;
  // reducer/publisher mapping: thread -> (row rr, col-quad cc4)
  const int  rr  = tid >> 5;          // 0..15
  const int  cc4 = tid & 31;          // 0..31 (4 cols each)
  const long pubOff = (long)(bg * 16 + rr) * H_ + cg * 128 + cc4 * 4;

  union { _Float16 h[4]; u64 q; } xc, xn;
  xc.q = *(const u64*)(xp + pubOff);  // xp(0)
  xn.q = 0;

  for (int t = 0; t < T_; ++t){
    // ---- poll h(t): 4 x 16B coherent loads from ONE producer ----
    const _Float16* hb = hring + (long)(t & (RING - 1)) * BH + haOff;
    u32x4 q[4];
    #pragma unroll
    for (int c = 0; c < 4; c++) q[c] = ld_b128_cohere(hb + c * 32);
    asm volatile("s_waitcnt vmcnt(0)" ::: "memory");
    __builtin_amdgcn_sched_barrier(0);

    f32x4 acc[8];
    #pragma unroll
    for (int ct = 0; ct < 8; ct++) acc[ct] = { 0.f, 0.f, 0.f, 0.f };

    unsigned need = 0xFu;
    while (true){
      #pragma unroll
      for (int c = 0; c < 4; c++){
        if (need & (1u << c)){
          bool bad = ((q[c][0] & 0xFFFFu) == 0xFFFFu) ||
                     ((q[c][2] & 0xFFFFu) == 0xFFFFu);
          if (!__any(bad)){
            union { u32x4 u; f16x8 v; } hu; hu.u = q[c];
            #pragma unroll
            for (int ct = 0; ct < 8; ct++)
              acc[ct] = __builtin_amdgcn_mfma_f32_16x16x32_f16(hu.v, wh[ct][c], acc[ct], 0, 0, 0);
            need &= ~(1u << c);
          }
        }
      }
      if (!need) break;
      #pragma unroll
      for (int c = 0; c < 4; c++)
        if (need & (1u << c)) q[c] = ld_b128_cohere(hb + c * 32);
      asm volatile("s_waitcnt vmcnt(0)" ::: "memory");
      __builtin_amdgcn_sched_barrier(0);
    }

    // ---- xp prefetch for t+1: issued EARLY (max flight before next drain) ----
    if (t + 1 < T_)
      xn.q = *(const u64*)(xp + (long)(t + 1) * BH + pubOff);

    // ---- partials to LDS (parity buffer); single lgkm-only barrier ----
    {
      float (*buf)[16][132] = part[t & 1];
      #pragma unroll
      for (int ct = 0; ct < 8; ct++)
        #pragma unroll
        for (int j = 0; j < 4; j++)
          buf[w][kq * 4 + j][ct * 16 + r16] = acc[ct][j];
    }
    asm volatile("s_waitcnt lgkmcnt(0)\n\ts_barrier" ::: "memory");

    // ---- reduce 8 waves' partials + xp, tanh, publish ----
    {
      const float (*buf)[16][132] = part[t & 1];
      f32x4 s = *(const f32x4*)&buf[0][rr][cc4 * 4];
      #pragma unroll
      for (int p = 1; p < 8; p++)
        s += *(const f32x4*)&buf[p][rr][cc4 * 4];
      float hv[4];
      #pragma unroll
      for (int j = 0; j < 4; j++){
        float v = s[j] + (float)xc.h[j];
        float a = fabsf(v), ex = __expf(-2.f * a);
        hv[j] = copysignf((1.f - ex) / (1.f + ex), v);
      }

      if (t < T_ - 1){
        union { _Float16 h[4]; u64 q; } g;
        #pragma unroll
        for (int j = 0; j < 4; j++) g.h[j] = (_Float16)hv[j];
        st_agent_u64((u64*)(hring + (long)((t + 1) & (RING - 1)) * BH + pubOff), g.q);
        if (t + 8 < T_)
          st_agent_u64((u64*)(hring + (long)((t + 8) & (RING - 1)) * BH + pubOff),
                       0xFFFFFFFFFFFFFFFFull);
      } else {
        *(float4*)(hT + pubOff) = make_float4(hv[0], hv[1], hv[2], hv[3]);
      }
    }
    // (barrier-2 deleted: parity dbuf makes next-step writes WAR-safe)
    xc.q = xn.q;
  }
}

// ---------------------------------------------------------------------------
// Head: y1 = relu(hT @ fc1_w^T + b1);  out = y1 @ fc2_w^T + b2   (all fp32)
// ---------------------------------------------------------------------------
__global__ void fc1_kernel(const float* __restrict__ hT, const float* __restrict__ w1,
                           const float* __restrict__ b1, float* __restrict__ y1)
{
  int o = blockIdx.x * 256 + threadIdx.x;     // 0..65535
  int b = o >> 10, j = o & 1023;
  const float4* hp = (const float4*)(hT + (long)b * H_);
  const float4* wp = (const float4*)(w1 + (long)j * H_);
  float s = 0.f;
  #pragma unroll 4
  for (int k = 0; k < H_ / 4; k++){
    float4 hv = hp[k], wv = wp[k];
    s += hv.x * wv.x + hv.y * wv.y + hv.z * wv.z + hv.w * wv.w;
  }
  s += b1[j];
  y1[o] = s > 0.f ? s : 0.f;
}

__global__ void fc2_kernel(const float* __restrict__ y1, const float* __restrict__ w2,
                           const float* __restrict__ b2, float* __restrict__ out)
{
  __shared__ float ybuf[H_];
  int b = blockIdx.x;
  for (int k = threadIdx.x; k < H_; k += 256) ybuf[k] = y1[(long)b * H_ + k];
  __syncthreads();
  if (threadIdx.x < C_){
    const float* wp = w2 + (long)threadIdx.x * H_;
    float s = 0.f;
    for (int k = 0; k < H_; k++) s += ybuf[k] * wp[k];
    out[b * C_ + threadIdx.x] = s + b2[threadIdx.x];
  }
}

// ---------------------------------------------------------------------------
extern "C" void kernel_launch(void* const* d_in, const int* in_sizes, int n_in,
                              void* d_out, int out_size, void* d_ws, size_t ws_size,
                              hipStream_t stream)
{
  const float* x   = (const float*)d_in[0];
  const float* wih = (const float*)d_in[1];
  const float* whh = (const float*)d_in[2];
  const float* bih = (const float*)d_in[3];
  const float* bhh = (const float*)d_in[4];
  const float* w1  = (const float*)d_in[5];
  const float* b1  = (const float*)d_in[6];
  const float* w2  = (const float*)d_in[7];
  const float* b2  = (const float*)d_in[8];
  float* out = (float*)d_out;

  char* ws = (char*)d_ws;
  size_t off = 0;
  auto carve = [&](size_t bytes) -> char* {
    char* p = ws + off; off += (bytes + 255) & ~(size_t)255; return p;
  };
  _Float16* whhF  = (_Float16*)carve((size_t)H_ * H_ * 2);
  _Float16* wihF  = (_Float16*)carve((size_t)H_ * E_ * 2);
  _Float16* hring = (_Float16*)carve((size_t)RING * BH * 2);
  float*    hT    = (float*)carve((size_t)B_ * H_ * 4);
  float*    y1    = (float*)carve((size_t)B_ * H_ * 4);
  _Float16* xp    = (_Float16*)carve((size_t)T_ * BH * 2);   // 64 MB, plain

  prep_kernel<<<1024, 256, 0, stream>>>(wih, whh, whhF, wihF, (short*)hring);
  xp_gemm<<<512, 256, 0, stream>>>(x, wihF, bih, bhh, xp);
  rnn_scan<<<32, 512, 0, stream>>>(xp, whhF, hring, hT);
  fc1_kernel<<<256, 256, 0, stream>>>(hT, w1, b1, y1);
  fc2_kernel<<<64, 256, 0, stream>>>(y1, w2, b2, out);
}

// Round 17
// 1575.322 us; speedup vs baseline: 4.7156x; 1.1077x over previous
//
#include <hip/hip_runtime.h>

#define B_ 64
#define T_ 512
#define E_ 512
#define H_ 1024
#define C_ 20
#define RING 16
#define BH (B_ * H_)

typedef __attribute__((ext_vector_type(8))) _Float16 f16x8;
typedef __attribute__((ext_vector_type(4))) float f32x4;
typedef __attribute__((ext_vector_type(4))) unsigned int u32x4;
typedef unsigned long long u64;

__device__ __forceinline__ void st_agent_u64(u64* p, u64 v){
  __hip_atomic_store(p, v, __ATOMIC_RELAXED, __HIP_MEMORY_SCOPE_AGENT);
}
// Coherent 16B load (bypasses L1/L2, reads the device-coherent point).
// Issued AND consumed within one loop iteration only (R13/R14 lesson:
// asm dests must not live across the back edge; compiler atomics serialize).
__device__ __forceinline__ u32x4 ld_b128_cohere(const void* p){
  u32x4 r;
  asm volatile("global_load_dwordx4 %0, %1, off sc0 sc1"
               : "=v"(r) : "v"(p) : "memory");
  return r;
}

// ---------------------------------------------------------------------------
// Prep: W_hh/W_ih -> fp16, init h-ring (slot0 = h0 = zeros, slots 1..15 =
// 0xFFFF sentinel = fp16 NaN, never produced by tanh). Ring MUST be re-inited
// every launch (ws not re-poisoned between graph replays).
// ---------------------------------------------------------------------------
__global__ void prep_kernel(const float* __restrict__ wih,
                            const float* __restrict__ whh,
                            _Float16* __restrict__ whhF,
                            _Float16* __restrict__ wihF,
                            short* __restrict__ hring)
{
  const long NH = (long)H_ * H_;
  const long NI = (long)H_ * E_;
  const long NR = (long)RING * BH;
  const long TOT = NH + NI + NR;
  long i = (long)blockIdx.x * blockDim.x + threadIdx.x;
  const long stride = (long)gridDim.x * blockDim.x;
  for (; i < TOT; i += stride){
    if (i < NH){
      whhF[i] = (_Float16)whh[i];
    } else if (i < NH + NI){
      long j = i - NH;
      wihF[j] = (_Float16)wih[j];
    } else {
      long j = i - NH - NI;
      hring[j] = (j < BH) ? (short)0 : (short)0xFFFF;
    }
  }
}

// ---------------------------------------------------------------------------
// xp_gemm: xp[t][b][h] = x[b][t][:] @ W_ih[h][:] + b_ih[h] + b_hh[h], fp16,
// stored PLAIN [t][b][h] (the scan adds xp at the reducer stage: 4 contiguous
// fp16 = one 8B read per thread).
// ---------------------------------------------------------------------------
__global__ __launch_bounds__(256, 1) void xp_gemm(
    const float* __restrict__ x, const _Float16* __restrict__ wihF,
    const float* __restrict__ bih, const float* __restrict__ bhh,
    _Float16* __restrict__ xp)
{
  const int lane = threadIdx.x & 63;
  const int wv   = threadIdx.x >> 6;       // 0..3 -> col quarter
  const int bg   = blockIdx.x & 3;
  const int tb   = (blockIdx.x >> 2) * 4;  // 4 timesteps per block
  const int r16  = lane & 15;
  const int k8   = (lane >> 4) * 8;

  const int brow = bg * 16 + r16;

  f32x4 acc[4][16];
  #pragma unroll
  for (int t = 0; t < 4; t++)
    #pragma unroll
    for (int c = 0; c < 16; c++) acc[t][c] = { 0.f, 0.f, 0.f, 0.f };

  for (int kc = 0; kc < 16; kc++){
    f16x8 a[4];
    #pragma unroll
    for (int t = 0; t < 4; t++){
      const float* xp8 = x + ((long)brow * T_ + tb + t) * E_ + kc * 32 + k8;
      float4 f0 = *(const float4*)xp8;
      float4 f1 = *(const float4*)(xp8 + 4);
      f16x8 v;
      v[0]=(_Float16)f0.x; v[1]=(_Float16)f0.y; v[2]=(_Float16)f0.z; v[3]=(_Float16)f0.w;
      v[4]=(_Float16)f1.x; v[5]=(_Float16)f1.y; v[6]=(_Float16)f1.z; v[7]=(_Float16)f1.w;
      a[t] = v;
    }
    #pragma unroll
    for (int c = 0; c < 16; c++){
      f16x8 b = *(const f16x8*)(wihF + (long)(wv * 256 + c * 16 + r16) * E_ + kc * 32 + k8);
      #pragma unroll
      for (int t = 0; t < 4; t++)
        acc[t][c] = __builtin_amdgcn_mfma_f32_16x16x32_f16(a[t], b, acc[t][c], 0, 0, 0);
    }
  }
  // C-frag: col = wv*256 + c*16 + (lane&15); row = bg*16 + (lane>>4)*4 + j
  #pragma unroll
  for (int c = 0; c < 16; c++){
    int col = wv * 256 + c * 16 + r16;
    float bs = bih[col] + bhh[col];
    #pragma unroll
    for (int t = 0; t < 4; t++){
      #pragma unroll
      for (int j = 0; j < 4; j++){
        int row = bg * 16 + (lane >> 4) * 4 + j;
        xp[((long)(tb + t)) * BH + (long)row * H_ + col] =
            (_Float16)(acc[t][c][j] + bs);
      }
    }
  }
}

// ---------------------------------------------------------------------------
// Persistent scan v8 (R12, best verified: 1403us scan / 1577us total).
// 32 blocks (4 bg x 8 cg) x 512 threads (8 waves). Block owns [16 rows x
// 128 cols]; K=1024 split over 8 waves (128 K each). Wave w's K-slice lies
// entirely inside producer block (bg, w): FAN-IN 1 PER WAVE, poll payload
// 4 KB/wave (4 x 16B per lane). Weights 32 KB/wave = 128 VGPRs, pinned.
//
// Per-step pipeline discipline:
//  - poll loads are the ONLY vmem in flight during the poll (vmcnt(0) per
//    round is cheap);
//  - xp(t+1) prefetch (one 8B cached load) is issued immediately AFTER the
//    poll loop exits -> ~0.5-0.7 us of flight before the next vmcnt(0)
//    drain, HBM latency fully hidden; consumed at the next reducer stage.
//  - partials in one 66 KB LDS buffer; TWO lgkm-only barriers per step
//    (write->reduce, read->next-write WAR). R16 lesson: barrier-2 is NOT
//    dead weight — it keeps the 8 waves in lockstep at step entry, bounding
//    producer-publish skew; deleting it cost 12%.
//  - publish BEFORE barrier-2 for earliest producer visibility.
// Exchange protocol (proven R4-R12): 16-slot sentinel ring, 8B single-copy-
// atomic granules, 0xFFFF fp16-NaN sentinel, re-sentinel slot t+8,
// arrival-order fused MFMAs, relaxed agent stores, bulk asm coherent loads.
// ---------------------------------------------------------------------------
__global__ __launch_bounds__(512, 1) void rnn_scan(
    const _Float16* __restrict__ xp, const _Float16* __restrict__ whhF,
    _Float16* __restrict__ hring, float* __restrict__ hT)
{
  const int tid  = threadIdx.x;
  const int lane = tid & 63;
  const int w    = tid >> 6;          // wave 0..7: K-slice == producer cg'
  const int bg   = blockIdx.x & 3;    // batch group (16 rows)
  const int cg   = blockIdx.x >> 2;   // col group 0..7 (128 cols)
  const int r16  = lane & 15;
  const int kq   = lane >> 4;         // 0..3

  __shared__ float part[8][16][132];  // [wave][row][col(+pad)] = 66 KB

  // --- pinned W_hh fragments: [col-tile ct 0..7][K-chunk kc 0..3] ---
  f16x8 wh[8][4];
  #pragma unroll
  for (int ct = 0; ct < 8; ct++)
    #pragma unroll
    for (int kc = 0; kc < 4; kc++)
      wh[ct][kc] = *(const f16x8*)(whhF +
          (long)(cg * 128 + ct * 16 + r16) * H_ + w * 128 + kc * 32 + kq * 8);
  #pragma unroll
  for (int ct = 0; ct < 8; ct++)
    #pragma unroll
    for (int kc = 0; kc < 4; kc++)
      asm volatile("" : "+v"(wh[ct][kc]));

  // consumer A-frag base: row = bg*16 + r16, K = w*128 + kc*32 + kq*8
  const long haOff = (long)(bg * 16 + r16) * H_ + w * 128 + kq * 8;
  // reducer/publisher mapping: thread -> (row rr, col-quad cc4)
  const int  rr  = tid >> 5;          // 0..15
  const int  cc4 = tid & 31;          // 0..31 (4 cols each)
  const long pubOff = (long)(bg * 16 + rr) * H_ + cg * 128 + cc4 * 4;

  union { _Float16 h[4]; u64 q; } xc, xn;
  xc.q = *(const u64*)(xp + pubOff);  // xp(0)
  xn.q = 0;

  for (int t = 0; t < T_; ++t){
    // ---- poll h(t): 4 x 16B coherent loads from ONE producer ----
    const _Float16* hb = hring + (long)(t & (RING - 1)) * BH + haOff;
    u32x4 q[4];
    #pragma unroll
    for (int c = 0; c < 4; c++) q[c] = ld_b128_cohere(hb + c * 32);
    asm volatile("s_waitcnt vmcnt(0)" ::: "memory");
    __builtin_amdgcn_sched_barrier(0);

    f32x4 acc[8];
    #pragma unroll
    for (int ct = 0; ct < 8; ct++) acc[ct] = { 0.f, 0.f, 0.f, 0.f };

    unsigned need = 0xFu;
    while (true){
      #pragma unroll
      for (int c = 0; c < 4; c++){
        if (need & (1u << c)){
          bool bad = ((q[c][0] & 0xFFFFu) == 0xFFFFu) ||
                     ((q[c][2] & 0xFFFFu) == 0xFFFFu);
          if (!__any(bad)){
            union { u32x4 u; f16x8 v; } hu; hu.u = q[c];
            #pragma unroll
            for (int ct = 0; ct < 8; ct++)
              acc[ct] = __builtin_amdgcn_mfma_f32_16x16x32_f16(hu.v, wh[ct][c], acc[ct], 0, 0, 0);
            need &= ~(1u << c);
          }
        }
      }
      if (!need) break;
      #pragma unroll
      for (int c = 0; c < 4; c++)
        if (need & (1u << c)) q[c] = ld_b128_cohere(hb + c * 32);
      asm volatile("s_waitcnt vmcnt(0)" ::: "memory");
      __builtin_amdgcn_sched_barrier(0);
    }

    // ---- xp prefetch for t+1: issued EARLY (max flight before next drain) ----
    if (t + 1 < T_)
      xn.q = *(const u64*)(xp + (long)(t + 1) * BH + pubOff);

    // ---- partials to LDS; barrier 1 (lgkm-only) ----
    #pragma unroll
    for (int ct = 0; ct < 8; ct++)
      #pragma unroll
      for (int j = 0; j < 4; j++)
        part[w][kq * 4 + j][ct * 16 + r16] = acc[ct][j];
    asm volatile("s_waitcnt lgkmcnt(0)\n\ts_barrier" ::: "memory");

    // ---- reduce 8 waves' partials + xp, tanh, publish ----
    {
      f32x4 s = *(const f32x4*)&part[0][rr][cc4 * 4];
      #pragma unroll
      for (int p = 1; p < 8; p++)
        s += *(const f32x4*)&part[p][rr][cc4 * 4];
      float hv[4];
      #pragma unroll
      for (int j = 0; j < 4; j++){
        float v = s[j] + (float)xc.h[j];
        float a = fabsf(v), ex = __expf(-2.f * a);
        hv[j] = copysignf((1.f - ex) / (1.f + ex), v);
      }

      if (t < T_ - 1){
        union { _Float16 h[4]; u64 q; } g;
        #pragma unroll
        for (int j = 0; j < 4; j++) g.h[j] = (_Float16)hv[j];
        st_agent_u64((u64*)(hring + (long)((t + 1) & (RING - 1)) * BH + pubOff), g.q);
        if (t + 8 < T_)
          st_agent_u64((u64*)(hring + (long)((t + 8) & (RING - 1)) * BH + pubOff),
                       0xFFFFFFFFFFFFFFFFull);
      } else {
        *(float4*)(hT + pubOff) = make_float4(hv[0], hv[1], hv[2], hv[3]);
      }
    }
    // ---- barrier 2: protect this step's LDS reads from next step's writes
    //      (and keep the 8 waves lockstepped at step entry — R16 lesson) ----
    asm volatile("s_waitcnt lgkmcnt(0)\n\ts_barrier" ::: "memory");
    xc.q = xn.q;
  }
}

// ---------------------------------------------------------------------------
// Head: y1 = relu(hT @ fc1_w^T + b1);  out = y1 @ fc2_w^T + b2   (all fp32)
// ---------------------------------------------------------------------------
__global__ void fc1_kernel(const float* __restrict__ hT, const float* __restrict__ w1,
                           const float* __restrict__ b1, float* __restrict__ y1)
{
  int o = blockIdx.x * 256 + threadIdx.x;     // 0..65535
  int b = o >> 10, j = o & 1023;
  const float4* hp = (const float4*)(hT + (long)b * H_);
  const float4* wp = (const float4*)(w1 + (long)j * H_);
  float s = 0.f;
  #pragma unroll 4
  for (int k = 0; k < H_ / 4; k++){
    float4 hv = hp[k], wv = wp[k];
    s += hv.x * wv.x + hv.y * wv.y + hv.z * wv.z + hv.w * wv.w;
  }
  s += b1[j];
  y1[o] = s > 0.f ? s : 0.f;
}

__global__ void fc2_kernel(const float* __restrict__ y1, const float* __restrict__ w2,
                           const float* __restrict__ b2, float* __restrict__ out)
{
  __shared__ float ybuf[H_];
  int b = blockIdx.x;
  for (int k = threadIdx.x; k < H_; k += 256) ybuf[k] = y1[(long)b * H_ + k];
  __syncthreads();
  if (threadIdx.x < C_){
    const float* wp = w2 + (long)threadIdx.x * H_;
    float s = 0.f;
    for (int k = 0; k < H_; k++) s += ybuf[k] * wp[k];
    out[b * C_ + threadIdx.x] = s + b2[threadIdx.x];
  }
}

// ---------------------------------------------------------------------------
extern "C" void kernel_launch(void* const* d_in, const int* in_sizes, int n_in,
                              void* d_out, int out_size, void* d_ws, size_t ws_size,
                              hipStream_t stream)
{
  const float* x   = (const float*)d_in[0];
  const float* wih = (const float*)d_in[1];
  const float* whh = (const float*)d_in[2];
  const float* bih = (const float*)d_in[3];
  const float* bhh = (const float*)d_in[4];
  const float* w1  = (const float*)d_in[5];
  const float* b1  = (const float*)d_in[6];
  const float* w2  = (const float*)d_in[7];
  const float* b2  = (const float*)d_in[8];
  float* out = (float*)d_out;

  char* ws = (char*)d_ws;
  size_t off = 0;
  auto carve = [&](size_t bytes) -> char* {
    char* p = ws + off; off += (bytes + 255) & ~(size_t)255; return p;
  };
  _Float16* whhF  = (_Float16*)carve((size_t)H_ * H_ * 2);
  _Float16* wihF  = (_Float16*)carve((size_t)H_ * E_ * 2);
  _Float16* hring = (_Float16*)carve((size_t)RING * BH * 2);
  float*    hT    = (float*)carve((size_t)B_ * H_ * 4);
  float*    y1    = (float*)carve((size_t)B_ * H_ * 4);
  _Float16* xp    = (_Float16*)carve((size_t)T_ * BH * 2);   // 64 MB, plain

  prep_kernel<<<1024, 256, 0, stream>>>(wih, whh, whhF, wihF, (short*)hring);
  xp_gemm<<<512, 256, 0, stream>>>(x, wihF, bih, bhh, xp);
  rnn_scan<<<32, 512, 0, stream>>>(xp, whhF, hring, hT);
  fc1_kernel<<<256, 256, 0, stream>>>(hT, w1, b1, y1);
  fc2_kernel<<<64, 256, 0, stream>>>(y1, w2, b2, out);
}